// Round 1
// baseline (1980.494 us; speedup 1.0000x reference)
//
#include <hip/hip_runtime.h>
#include <hip/hip_bf16.h>
#include <stdint.h>

// Problem constants
#define B_    16
#define C_    512
#define HIMG  56
#define N_    3136
#define NK_   49
#define NH_   8
#define HD_   64
#define JP_   52          // padded NK (49 -> 52) so 8*52 = 416 = 13*32
#define J_    416
#define HID_  24
#define CNT_  1229312.0f  // 8 * 3136 * 49 (elements per group-norm group)
#define EPS_  1e-5f
#define SCALE_ 0.125f     // HEAD_DIM^-0.5

typedef __attribute__((ext_vector_type(8))) short short8;
typedef __attribute__((ext_vector_type(4))) float floatx4;

static __device__ __forceinline__ uint16_t f2bf(float f) {
  uint32_t u = __builtin_bit_cast(uint32_t, f);
  u = (u + 0x7FFFu + ((u >> 16) & 1u)) >> 16;
  return (uint16_t)u;
}
static __device__ __forceinline__ float bf2f(uint16_t h) {
  uint32_t u = ((uint32_t)h) << 16;
  return __builtin_bit_cast(float, u);
}
static __device__ __forceinline__ float sigm(float x) {
  return 1.0f / (1.0f + __expf(-x));
}

// ---------------------------------------------------------------------------
// 1) kvx[b][m][c] = sum_{i,j} x[b][c][(8ph+i)*56 + 8pw+j] * down_w[c][i][j]
// ---------------------------------------------------------------------------
__global__ __launch_bounds__(256) void k_kvx(const float* __restrict__ x,
                                             const float* __restrict__ dw,
                                             float* __restrict__ kvx) {
  int g = blockIdx.x * 256 + threadIdx.x;           // B*C*NK = 401408 exact
  int b = g / (C_ * NK_);
  int rem = g % (C_ * NK_);
  int c = rem / NK_;
  int m = rem % NK_;
  int ph = m / 7, pw = m % 7;
  const float* xp = x + ((size_t)(b * C_ + c)) * N_ + (ph * 8) * HIMG + pw * 8;
  const float* wp = dw + c * 64;
  float acc = 0.f;
#pragma unroll
  for (int i = 0; i < 8; ++i) {
    float4 a  = *(const float4*)(xp + i * HIMG);
    float4 bq = *(const float4*)(xp + i * HIMG + 4);
    acc += a.x*wp[i*8+0] + a.y*wp[i*8+1] + a.z*wp[i*8+2] + a.w*wp[i*8+3]
         + bq.x*wp[i*8+4] + bq.y*wp[i*8+5] + bq.z*wp[i*8+6] + bq.w*wp[i*8+7];
  }
  kvx[((size_t)(b * NK_ + m)) * C_ + c] = acc;
}

// ---------------------------------------------------------------------------
// 2) kv[b][m][col] = sum_c kvx[b][m][c] * kv_w[c][col]   (col 0..1023)
// ---------------------------------------------------------------------------
__global__ __launch_bounds__(256) void k_kv(const float* __restrict__ kvx,
                                            const float* __restrict__ kv_w,
                                            float* __restrict__ kv) {
  int b = blockIdx.x;   // 16
  int rg = blockIdx.y;  // 7 row groups of 8 (last has 1)
  int m0 = rg * 8;
  int nr = min(8, NK_ - m0);
  __shared__ float ks[8 * C_];
  for (int idx = threadIdx.x; idx < 8 * C_; idx += 256)
    ks[idx] = (idx < nr * C_) ? kvx[((size_t)(b * NK_ + m0)) * C_ + idx] : 0.f;
  __syncthreads();
  int j4 = threadIdx.x * 4;
  float4 acc[8];
#pragma unroll
  for (int i = 0; i < 8; ++i) acc[i] = make_float4(0,0,0,0);
  for (int c = 0; c < C_; ++c) {
    float4 w = *(const float4*)(kv_w + (size_t)c * 1024 + j4);
#pragma unroll
    for (int i = 0; i < 8; ++i) {
      float a = ks[i * C_ + c];
      acc[i].x += a*w.x; acc[i].y += a*w.y; acc[i].z += a*w.z; acc[i].w += a*w.w;
    }
  }
  for (int i = 0; i < nr; ++i)
    *(float4*)(kv + ((size_t)(b * NK_ + m0 + i)) * 1024 + j4) = acc[i];
}

// ---------------------------------------------------------------------------
// 3) wqkT[b][h*52+m][c] = SCALE * sum_d q_w[c][h*64+d] * k[b][h][m][d]  (bf16)
//    pads (m=49..51) zeroed.
// ---------------------------------------------------------------------------
__global__ __launch_bounds__(256) void k_wqk(const float* __restrict__ kv,
                                             const float* __restrict__ q_w,
                                             uint16_t* __restrict__ wqkT) {
  int b = blockIdx.x, h = blockIdx.y;
  __shared__ float ksm[56 * 64];
  for (int idx = threadIdx.x; idx < 56 * 64; idx += 256) {
    int m = idx >> 6, d = idx & 63;
    ksm[idx] = (m < NK_) ? kv[((size_t)(b * NK_ + m)) * 1024 + h * HD_ + d] : 0.f;
  }
  __syncthreads();
#pragma unroll
  for (int cc = 0; cc < 2; ++cc) {
    int c = threadIdx.x + cc * 256;
    float qrow[64];
    const float* qp = q_w + (size_t)c * C_ + h * HD_;
#pragma unroll
    for (int d = 0; d < 64; ++d) qrow[d] = qp[d];
    for (int mc = 0; mc < NK_; mc += 8) {
      int cnt = min(8, NK_ - mc);
      float acc[8] = {0,0,0,0,0,0,0,0};
      for (int d = 0; d < 64; ++d) {
        float q = qrow[d];
#pragma unroll
        for (int i = 0; i < 8; ++i) acc[i] += q * ksm[(mc + i) * 64 + d];
      }
      for (int i = 0; i < cnt; ++i)
        wqkT[((size_t)(b * J_ + h * JP_ + mc + i)) * C_ + c] = f2bf(acc[i] * SCALE_);
    }
  }
  for (int idx = threadIdx.x; idx < 3 * C_; idx += 256) {
    int rr = idx / C_, c = idx % C_;
    wqkT[((size_t)(b * J_ + h * JP_ + 49 + rr)) * C_ + c] = 0;
  }
}

// ---------------------------------------------------------------------------
// 4) wvT[b][c'][h*52+m] = sum_d v[b][h][m][d] * proj_w[h*64+d][c']  (bf16)
//    pads (m=49..51) zeroed  -> pad rows contribute 0 in final GEMM.
// ---------------------------------------------------------------------------
__global__ __launch_bounds__(256) void k_wv(const float* __restrict__ kv,
                                            const float* __restrict__ proj_w,
                                            uint16_t* __restrict__ wvT) {
  int b = blockIdx.x, h = blockIdx.y;
  __shared__ float vsm[56 * 64];
  for (int idx = threadIdx.x; idx < 56 * 64; idx += 256) {
    int m = idx >> 6, d = idx & 63;
    vsm[idx] = (m < NK_) ? kv[((size_t)(b * NK_ + m)) * 1024 + 512 + h * HD_ + d] : 0.f;
  }
  __syncthreads();
#pragma unroll
  for (int cc = 0; cc < 2; ++cc) {
    int c = threadIdx.x + cc * 256;  // output column c'
    for (int mc = 0; mc < NK_; mc += 8) {
      int cnt = min(8, NK_ - mc);
      float acc[8] = {0,0,0,0,0,0,0,0};
      for (int d = 0; d < 64; ++d) {
        float w = proj_w[(size_t)(h * HD_ + d) * C_ + c];
#pragma unroll
        for (int i = 0; i < 8; ++i) acc[i] += vsm[(mc + i) * 64 + d] * w;
      }
      uint16_t* dst = wvT + ((size_t)(b * C_ + c)) * J_ + h * JP_ + mc;
      if (cnt == 8) {
        uint32_t pk[4];
#pragma unroll
        for (int i = 0; i < 4; ++i)
          pk[i] = (uint32_t)f2bf(acc[2*i]) | ((uint32_t)f2bf(acc[2*i+1]) << 16);
        *(uint2*)(dst)     = make_uint2(pk[0], pk[1]);
        *(uint2*)(dst + 4) = make_uint2(pk[2], pk[3]);
      } else {
        for (int i = 0; i < cnt; ++i) dst[i] = f2bf(acc[i]);
      }
    }
    uint16_t* pd = wvT + ((size_t)(b * C_ + c)) * J_ + h * JP_ + 49;
    pd[0] = 0; pd[1] = 0; pd[2] = 0;
  }
}

// ---------------------------------------------------------------------------
// 5) GEMM1 + softmax:  logits[n][j] = sum_c x[b][c][n] * wqkT[b][j][c]
//    tile M=64 rows(n), N=208 cols(4 heads*52), K=32, 16 K-steps; then
//    softmax over m<49 per (row, head) with rel_bias; write attn (fp32).
// ---------------------------------------------------------------------------
__global__ __launch_bounds__(256) void k_attn(const float* __restrict__ x,
                                              const uint16_t* __restrict__ wqkT,
                                              const float* __restrict__ rel_bias,
                                              float* __restrict__ attn) {
  const int mt = blockIdx.x, ct = blockIdx.y, b = blockIdx.z;
  const int n0 = mt * 64, j0 = ct * 208;
  const int tid = threadIdx.x, wvid = tid >> 6, lane = tid & 63;
  __shared__ __align__(16) char smem[64 * 212 * 4];   // 54272 B; staging aliased
  uint32_t* A32 = (uint32_t*)smem;          // [64][20] u32 (2 bf16 each)
  uint32_t* B32 = A32 + 64 * 20;            // [208][20]
  float* Ss = (float*)smem;                 // [64][212] epilogue (aliases staging)

  floatx4 acc[13];
#pragma unroll
  for (int t = 0; t < 13; ++t) acc[t] = (floatx4){0.f,0.f,0.f,0.f};

  const int an = tid & 63, acp = tid >> 6;  // A staging: row n (coalesced), c-group
  for (int ks = 0; ks < 16; ++ks) {
    const int c0 = ks * 32;
    __syncthreads();
    {  // stage A: x[c0+8*acp+i][n0+an] -> bf16 pairs along c
      const float* xb = x + ((size_t)b * C_ + c0 + acp * 8) * N_ + n0 + an;
      uint32_t pk[4];
#pragma unroll
      for (int jj = 0; jj < 4; ++jj) {
        float f0 = xb[(size_t)(2*jj) * N_];
        float f1 = xb[(size_t)(2*jj+1) * N_];
        pk[jj] = (uint32_t)f2bf(f0) | ((uint32_t)f2bf(f1) << 16);
      }
      *(uint4*)&A32[an * 20 + acp * 4] = make_uint4(pk[0], pk[1], pk[2], pk[3]);
    }
    for (int idx = tid; idx < 832; idx += 256) {  // stage B: 208 rows x 4 chunks
      int jl = idx >> 2, q = idx & 3;
      uint4 v = *(const uint4*)(wqkT + ((size_t)b * J_ + j0 + jl) * C_ + c0 + q * 8);
      *(uint4*)&B32[jl * 20 + q * 4] = v;
    }
    __syncthreads();
    short8 af = *(const short8*)&A32[(wvid * 16 + (lane & 15)) * 20 + (lane >> 4) * 4];
#pragma unroll
    for (int t = 0; t < 13; ++t) {
      short8 bfb = *(const short8*)&B32[(16 * t + (lane & 15)) * 20 + (lane >> 4) * 4];
      acc[t] = __builtin_amdgcn_mfma_f32_16x16x32_bf16(af, bfb, acc[t], 0, 0, 0);
    }
  }
  __syncthreads();
  {  // dump accumulators to LDS: D row=(lane>>4)*4+reg, col=lane&15
    const int rb = wvid * 16 + ((lane >> 4) << 2), cb = lane & 15;
#pragma unroll
    for (int t = 0; t < 13; ++t)
#pragma unroll
      for (int r2 = 0; r2 < 4; ++r2)
        Ss[(rb + r2) * 212 + t * 16 + cb] = acc[t][r2];
  }
  __syncthreads();
  {  // softmax per (row, head-in-tile)
    const int row = tid >> 2, hh = tid & 3;
    const int n = n0 + row;
    const float* bias = rel_bias + (size_t)n * NK_;
    float* srow = &Ss[row * 212 + hh * JP_];
    float mx = -1e30f;
    for (int m = 0; m < NK_; ++m) mx = fmaxf(mx, srow[m] + bias[m]);
    float sum = 0.f;
    for (int m = 0; m < NK_; ++m) { float e = __expf(srow[m] + bias[m] - mx); srow[m] = e; sum += e; }
    float inv = 1.f / sum;
    float* dst = attn + ((size_t)b * N_ + n) * J_ + j0 + hh * JP_;
    for (int m = 0; m < NK_; ++m) dst[m] = srow[m] * inv;
    dst[49] = 0.f; dst[50] = 0.f; dst[51] = 0.f;
  }
}

// ---------------------------------------------------------------------------
// 6) gn1 stats: a1[o] = sum_h ew[o][h]*attn[h] per pixel; accumulate
//    sum/sumsq per (b, group of 8 channels) -> gn1sums[b][g][2]
// ---------------------------------------------------------------------------
__global__ __launch_bounds__(256) void k_gn1stats(const float* __restrict__ attn,
                                                  const float* __restrict__ ew,
                                                  float* __restrict__ gsums) {
  int nt = blockIdx.x, b = blockIdx.y;  // 49 x 16
  __shared__ float ews[HID_ * NH_];
  __shared__ float red[4][8];
  for (int i = threadIdx.x; i < HID_ * NH_; i += 256) ews[i] = ew[i];
  __syncthreads();
  float s[3] = {0,0,0}, q[3] = {0,0,0};
  for (int task = threadIdx.x; task < 64 * NK_; task += 256) {
    int r = task / NK_, m = task % NK_;
    const float* ap = attn + ((size_t)b * N_ + nt * 64 + r) * J_ + m;
    float a[8];
#pragma unroll
    for (int h = 0; h < 8; ++h) a[h] = ap[h * JP_];
#pragma unroll
    for (int o = 0; o < HID_; ++o) {
      float v = 0.f;
#pragma unroll
      for (int h = 0; h < 8; ++h) v += ews[o * 8 + h] * a[h];
      s[o >> 3] += v; q[o >> 3] += v * v;
    }
  }
  int lane = threadIdx.x & 63, wvid = threadIdx.x >> 6;
#pragma unroll
  for (int g = 0; g < 3; ++g) {
    float vs = s[g], vq = q[g];
#pragma unroll
    for (int off = 32; off; off >>= 1) { vs += __shfl_down(vs, off, 64); vq += __shfl_down(vq, off, 64); }
    if (lane == 0) { red[wvid][g*2] = vs; red[wvid][g*2+1] = vq; }
  }
  __syncthreads();
  if (threadIdx.x < 6) {
    float t = red[0][threadIdx.x] + red[1][threadIdx.x] + red[2][threadIdx.x] + red[3][threadIdx.x];
    atomicAdd(&gsums[b * 6 + threadIdx.x], t);
  }
}

// ---------------------------------------------------------------------------
// 7) DLA tile pass (8 rows + halo, full 49 cols, 24 hidden channels):
//    pass=0: h1=swish(gn1(expand)), h2=dw3x3(h1) -> accumulate gn2 sums
//    pass=1: same + gn2+swish+reduce -> r (bf16, padded) + gn3 sums
// ---------------------------------------------------------------------------
__global__ __launch_bounds__(256) void k_dla(const float* __restrict__ attn,
    const float* __restrict__ ew, const float* __restrict__ gn1_s,
    const float* __restrict__ gn1_b, const float* __restrict__ dww,
    const float* __restrict__ gn1sums, int pass,
    const float* __restrict__ gn2_s, const float* __restrict__ gn2_b,
    const float* __restrict__ gn2sums, const float* __restrict__ rww,
    float* __restrict__ outsums, uint16_t* __restrict__ rbuf) {
  int nt = blockIdx.x, b = blockIdx.y;  // 392 x 16
  int n0 = nt * 8;
  __shared__ float h1s[10 * HID_ * NK_];  // 47040 B
  __shared__ float ews[HID_ * NH_];
  __shared__ float dws[HID_ * 9];
  __shared__ float ab1[HID_ * 2];
  __shared__ float ab2[HID_ * 2];
  __shared__ float rws[8 * HID_];
  __shared__ float red[4][8];

  for (int i = threadIdx.x; i < HID_ * NH_; i += 256) ews[i] = ew[i];
  for (int i = threadIdx.x; i < HID_ * 9; i += 256) dws[i] = dww[i];
  if (pass) for (int i = threadIdx.x; i < 8 * HID_; i += 256) rws[i] = rww[i];
  if (threadIdx.x < HID_) {
    int o = threadIdx.x, g = o >> 3;
    {
      float s = gn1sums[b*6 + g*2], qq = gn1sums[b*6 + g*2 + 1];
      float mean = s * (1.f / CNT_);
      float var = qq * (1.f / CNT_) - mean * mean;
      float inv = rsqrtf(var + EPS_);
      float al = inv * gn1_s[o];
      ab1[o*2] = al; ab1[o*2+1] = gn1_b[o] - mean * al;
    }
    if (pass) {
      float s = gn2sums[b*6 + g*2], qq = gn2sums[b*6 + g*2 + 1];
      float mean = s * (1.f / CNT_);
      float var = qq * (1.f / CNT_) - mean * mean;
      float inv = rsqrtf(var + EPS_);
      float al = inv * gn2_s[o];
      ab2[o*2] = al; ab2[o*2+1] = gn2_b[o] - mean * al;
    }
  }
  __syncthreads();
  // phase 1: h1 for rows n0-1 .. n0+8 (10 rows)
  for (int task = threadIdx.x; task < 490; task += 256) {
    int r = task / NK_, m = task % NK_;
    int n = n0 - 1 + r;
    if (n < 0 || n >= N_) {
#pragma unroll
      for (int o = 0; o < HID_; ++o) h1s[(r * HID_ + o) * NK_ + m] = 0.f;
    } else {
      const float* ap = attn + ((size_t)b * N_ + n) * J_ + m;
      float a[8];
#pragma unroll
      for (int h = 0; h < 8; ++h) a[h] = ap[h * JP_];
#pragma unroll
      for (int o = 0; o < HID_; ++o) {
        float v = 0.f;
#pragma unroll
        for (int h = 0; h < 8; ++h) v += ews[o * 8 + h] * a[h];
        float z = v * ab1[o*2] + ab1[o*2+1];
        h1s[(r * HID_ + o) * NK_ + m] = z * sigm(z);
      }
    }
  }
  __syncthreads();
  // phase 2: depthwise 3x3 + consume
  float sums[3] = {0,0,0}, sqs[3] = {0,0,0};
  float sr = 0.f, qr = 0.f;
  for (int task = threadIdx.x; task < 392; task += 256) {
    int row = task / NK_, m = task % NK_;
    float rloc[8] = {0,0,0,0,0,0,0,0};
#pragma unroll
    for (int o = 0; o < HID_; ++o) {
      float a2 = 0.f;
#pragma unroll
      for (int dr = 0; dr < 3; ++dr) {
        const float* hp = &h1s[((row + dr) * HID_ + o) * NK_ + m];
        const float* wp = &dws[o * 9 + dr * 3];
        if (m > 0)  a2 += hp[-1] * wp[0];
        a2 += hp[0] * wp[1];
        if (m < 48) a2 += hp[1] * wp[2];
      }
      if (pass == 0) {
        sums[o >> 3] += a2; sqs[o >> 3] += a2 * a2;
      } else {
        float z = a2 * ab2[o*2] + ab2[o*2+1];
        float sw = z * sigm(z);
#pragma unroll
        for (int p = 0; p < 8; ++p) rloc[p] += rws[p * HID_ + o] * sw;
      }
    }
    if (pass) {
      int n = n0 + row;
      uint16_t* dst = rbuf + ((size_t)b * N_ + n) * J_ + m;
#pragma unroll
      for (int p = 0; p < 8; ++p) {
        dst[p * JP_] = f2bf(rloc[p]);
        sr += rloc[p]; qr += rloc[p] * rloc[p];
      }
    }
  }
  if (pass) {  // zero pads m=49..51 for all 8 rows x 8 channels
    for (int idx = threadIdx.x; idx < 192; idx += 256) {
      int row = idx / 24, rm = idx % 24, p = rm / 3, mm = 49 + rm % 3;
      rbuf[((size_t)b * N_ + n0 + row) * J_ + p * JP_ + mm] = 0;
    }
  }
  int lane = threadIdx.x & 63, wvid = threadIdx.x >> 6;
  if (pass == 0) {
#pragma unroll
    for (int g = 0; g < 3; ++g) {
      float vs = sums[g], vq = sqs[g];
#pragma unroll
      for (int off = 32; off; off >>= 1) { vs += __shfl_down(vs, off, 64); vq += __shfl_down(vq, off, 64); }
      if (lane == 0) { red[wvid][g*2] = vs; red[wvid][g*2+1] = vq; }
    }
    __syncthreads();
    if (threadIdx.x < 6) {
      float t = red[0][threadIdx.x] + red[1][threadIdx.x] + red[2][threadIdx.x] + red[3][threadIdx.x];
      atomicAdd(&outsums[b * 6 + threadIdx.x], t);
    }
  } else {
    float vs = sr, vq = qr;
#pragma unroll
    for (int off = 32; off; off >>= 1) { vs += __shfl_down(vs, off, 64); vq += __shfl_down(vq, off, 64); }
    if (lane == 0) { red[wvid][0] = vs; red[wvid][1] = vq; }
    __syncthreads();
    if (threadIdx.x < 2) {
      float t = red[0][threadIdx.x] + red[1][threadIdx.x] + red[2][threadIdx.x] + red[3][threadIdx.x];
      atomicAdd(&outsums[b * 2 + threadIdx.x], t);
    }
  }
}

// ---------------------------------------------------------------------------
// 8) GEMM2: out[b][n][c'] = sum_j gn3(r)[n][j] * wvT[b][c'][j] + proj_b[c']
//    tile M=64(n), N=128(c'), K=32, 13 K-steps; gn3 applied in A staging.
// ---------------------------------------------------------------------------
__global__ __launch_bounds__(256) void k_out(const uint16_t* __restrict__ rr,
    const uint16_t* __restrict__ wvT, const float* __restrict__ gn3sums,
    const float* __restrict__ gn3_s, const float* __restrict__ gn3_b,
    const float* __restrict__ proj_b, float* __restrict__ outp) {
  const int mt = blockIdx.x, ct = blockIdx.y, b = blockIdx.z;
  const int n0 = mt * 64, c0 = ct * 128;
  const int tid = threadIdx.x, wvid = tid >> 6, lane = tid & 63;
  __shared__ __align__(16) uint32_t A32[64 * 20];
  __shared__ __align__(16) uint32_t B32[128 * 20];
  __shared__ float ab3[J_ * 2];
  {
    float ssum = gn3sums[b*2], sq = gn3sums[b*2+1];
    float mean = ssum * (1.f / CNT_);
    float var = sq * (1.f / CNT_) - mean * mean;
    float inv = rsqrtf(var + EPS_);
    for (int j = tid; j < J_; j += 256) {
      int h = j / JP_;
      float al = inv * gn3_s[h];
      ab3[j*2] = al; ab3[j*2+1] = gn3_b[h] - mean * al;
    }
  }
  floatx4 acc[8];
#pragma unroll
  for (int t = 0; t < 8; ++t) acc[t] = (floatx4){0.f,0.f,0.f,0.f};
  const int an = tid >> 2, acp = tid & 3;
  for (int ks = 0; ks < 13; ++ks) {
    const int k0 = ks * 32;
    __syncthreads();
    {  // stage A with gn3 affine
      const uint16_t* src = rr + ((size_t)b * N_ + n0 + an) * J_ + k0 + acp * 8;
      uint4 v = *(const uint4*)src;
      uint32_t raw[4] = {v.x, v.y, v.z, v.w};
      uint32_t pk[4];
#pragma unroll
      for (int jj = 0; jj < 4; ++jj) {
        int j = k0 + acp * 8 + jj * 2;
        float f0 = bf2f((uint16_t)(raw[jj] & 0xFFFFu)) * ab3[j*2]     + ab3[j*2+1];
        float f1 = bf2f((uint16_t)(raw[jj] >> 16))     * ab3[(j+1)*2] + ab3[(j+1)*2+1];
        pk[jj] = (uint32_t)f2bf(f0) | ((uint32_t)f2bf(f1) << 16);
      }
      *(uint4*)&A32[an * 20 + acp * 4] = make_uint4(pk[0], pk[1], pk[2], pk[3]);
    }
    for (int idx = tid; idx < 128 * 4; idx += 256) {
      int rw2 = idx >> 2, q = idx & 3;
      uint4 v = *(const uint4*)(wvT + ((size_t)b * C_ + c0 + rw2) * J_ + k0 + q * 8);
      *(uint4*)&B32[rw2 * 20 + q * 4] = v;
    }
    __syncthreads();
    short8 af = *(const short8*)&A32[(wvid * 16 + (lane & 15)) * 20 + (lane >> 4) * 4];
#pragma unroll
    for (int t = 0; t < 8; ++t) {
      short8 bfb = *(const short8*)&B32[(t * 16 + (lane & 15)) * 20 + (lane >> 4) * 4];
      acc[t] = __builtin_amdgcn_mfma_f32_16x16x32_bf16(af, bfb, acc[t], 0, 0, 0);
    }
  }
  const int rb = wvid * 16 + ((lane >> 4) << 2);
#pragma unroll
  for (int t = 0; t < 8; ++t) {
    int c = c0 + t * 16 + (lane & 15);
    float pb = proj_b[c];
#pragma unroll
    for (int r2 = 0; r2 < 4; ++r2)
      outp[((size_t)b * N_ + n0 + rb + r2) * C_ + c] = acc[t][r2] + pb;
  }
}

// ---------------------------------------------------------------------------
extern "C" void kernel_launch(void* const* d_in, const int* in_sizes, int n_in,
                              void* d_out, int out_size, void* d_ws, size_t ws_size,
                              hipStream_t stream) {
  (void)in_sizes; (void)n_in; (void)out_size;
  const float* x      = (const float*)d_in[0];
  const float* q_w    = (const float*)d_in[1];
  const float* down_w = (const float*)d_in[2];
  const float* kv_w   = (const float*)d_in[3];
  const float* proj_w = (const float*)d_in[4];
  const float* proj_b = (const float*)d_in[5];
  const float* rel_b  = (const float*)d_in[6];
  const float* ew     = (const float*)d_in[7];
  const float* gn1_s  = (const float*)d_in[8];
  const float* gn1_b  = (const float*)d_in[9];
  const float* dw_w   = (const float*)d_in[10];
  const float* gn2_s  = (const float*)d_in[11];
  const float* gn2_b  = (const float*)d_in[12];
  const float* red_w  = (const float*)d_in[13];
  const float* gn3_s  = (const float*)d_in[14];
  const float* gn3_b  = (const float*)d_in[15];
  float* outp = (float*)d_out;

  const size_t NEEDED = 143688704;  // ~137 MiB
  if (ws_size < NEEDED) return;     // fail loudly via absmax instead of segfault

  char* ws = (char*)d_ws;
  float*    kvx   = (float*)(ws);                    //  1,605,632 B
  float*    kv    = (float*)(ws + 1605632);          //  3,211,264 B
  uint16_t* wqkT  = (uint16_t*)(ws + 4816896);       //  6,815,744 B
  uint16_t* wvT   = (uint16_t*)(ws + 11632640);      //  6,815,744 B
  float*    attn  = (float*)(ws + 18448384);         // 83,492,864 B
  uint16_t* rbuf  = (uint16_t*)(ws + 101941248);     // 41,746,432 B
  float*    stats = (float*)(ws + 143687680);        //      1,024 B
  float* gn1sums = stats;        // 16*6
  float* gn2sums = stats + 96;   // 16*6
  float* gn3sums = stats + 192;  // 16*2

  hipMemsetAsync(stats, 0, 1024, stream);
  k_kvx<<<1568, 256, 0, stream>>>(x, down_w, kvx);
  k_kv<<<dim3(16, 7), 256, 0, stream>>>(kvx, kv_w, kv);
  k_wqk<<<dim3(16, 8), 256, 0, stream>>>(kv, q_w, wqkT);
  k_wv<<<dim3(16, 8), 256, 0, stream>>>(kv, proj_w, wvT);
  k_attn<<<dim3(49, 2, 16), 256, 0, stream>>>(x, wqkT, rel_b, attn);
  k_gn1stats<<<dim3(49, 16), 256, 0, stream>>>(attn, ew, gn1sums);
  k_dla<<<dim3(392, 16), 256, 0, stream>>>(attn, ew, gn1_s, gn1_b, dw_w, gn1sums, 0,
                                           gn2_s, gn2_b, gn2sums, red_w, gn2sums, nullptr);
  k_dla<<<dim3(392, 16), 256, 0, stream>>>(attn, ew, gn1_s, gn1_b, dw_w, gn1sums, 1,
                                           gn2_s, gn2_b, gn2sums, red_w, gn3sums, rbuf);
  k_out<<<dim3(49, 4, 16), 256, 0, stream>>>(rbuf, wvT, gn3sums, gn3_s, gn3_b, proj_b, outp);
}

// Round 2
// 1342.168 us; speedup vs baseline: 1.4756x; 1.4756x over previous
//
#include <hip/hip_runtime.h>
#include <hip/hip_bf16.h>
#include <stdint.h>

// Problem constants
#define B_    16
#define C_    512
#define HIMG  56
#define N_    3136
#define NK_   49
#define NH_   8
#define HD_   64
#define JP_   52          // padded NK (49 -> 52) so 8*52 = 416 = 13*32
#define J_    416
#define HID_  24
#define CNT_  1229312.0f  // 8 * 3136 * 49 (elements per group-norm group)
#define EPS_  1e-5f
#define SCALE_ 0.125f     // HEAD_DIM^-0.5

typedef __attribute__((ext_vector_type(8))) short short8;
typedef __attribute__((ext_vector_type(4))) float floatx4;

static __device__ __forceinline__ uint16_t f2bf(float f) {
  uint32_t u = __builtin_bit_cast(uint32_t, f);
  u = (u + 0x7FFFu + ((u >> 16) & 1u)) >> 16;
  return (uint16_t)u;
}
static __device__ __forceinline__ float bf2f(uint16_t h) {
  uint32_t u = ((uint32_t)h) << 16;
  return __builtin_bit_cast(float, u);
}
static __device__ __forceinline__ float sigm(float x) {
  return 1.0f / (1.0f + __expf(-x));
}

// ---------------------------------------------------------------------------
// 1) kvx[b][m][c] = sum_{i,j} x[b][c][(8ph+i)*56 + 8pw+j] * down_w[c][i][j]
// ---------------------------------------------------------------------------
__global__ __launch_bounds__(256) void k_kvx(const float* __restrict__ x,
                                             const float* __restrict__ dw,
                                             float* __restrict__ kvx) {
  int g = blockIdx.x * 256 + threadIdx.x;           // B*C*NK = 401408 exact
  int b = g / (C_ * NK_);
  int rem = g % (C_ * NK_);
  int c = rem / NK_;
  int m = rem % NK_;
  int ph = m / 7, pw = m % 7;
  const float* xp = x + ((size_t)(b * C_ + c)) * N_ + (ph * 8) * HIMG + pw * 8;
  const float* wp = dw + c * 64;
  float acc = 0.f;
#pragma unroll
  for (int i = 0; i < 8; ++i) {
    float4 a  = *(const float4*)(xp + i * HIMG);
    float4 bq = *(const float4*)(xp + i * HIMG + 4);
    acc += a.x*wp[i*8+0] + a.y*wp[i*8+1] + a.z*wp[i*8+2] + a.w*wp[i*8+3]
         + bq.x*wp[i*8+4] + bq.y*wp[i*8+5] + bq.z*wp[i*8+6] + bq.w*wp[i*8+7];
  }
  kvx[((size_t)(b * NK_ + m)) * C_ + c] = acc;
}

// ---------------------------------------------------------------------------
// 2) kv[b][m][col] = sum_c kvx[b][m][c] * kv_w[c][col]   (col 0..1023)
// ---------------------------------------------------------------------------
__global__ __launch_bounds__(256) void k_kv(const float* __restrict__ kvx,
                                            const float* __restrict__ kv_w,
                                            float* __restrict__ kv) {
  int b = blockIdx.x;   // 16
  int rg = blockIdx.y;  // 7 row groups of 8 (last has 1)
  int m0 = rg * 8;
  int nr = min(8, NK_ - m0);
  __shared__ float ks[8 * C_];
  for (int idx = threadIdx.x; idx < 8 * C_; idx += 256)
    ks[idx] = (idx < nr * C_) ? kvx[((size_t)(b * NK_ + m0)) * C_ + idx] : 0.f;
  __syncthreads();
  int j4 = threadIdx.x * 4;
  float4 acc[8];
#pragma unroll
  for (int i = 0; i < 8; ++i) acc[i] = make_float4(0,0,0,0);
  for (int c = 0; c < C_; ++c) {
    float4 w = *(const float4*)(kv_w + (size_t)c * 1024 + j4);
#pragma unroll
    for (int i = 0; i < 8; ++i) {
      float a = ks[i * C_ + c];
      acc[i].x += a*w.x; acc[i].y += a*w.y; acc[i].z += a*w.z; acc[i].w += a*w.w;
    }
  }
  for (int i = 0; i < nr; ++i)
    *(float4*)(kv + ((size_t)(b * NK_ + m0 + i)) * 1024 + j4) = acc[i];
}

// ---------------------------------------------------------------------------
// 3) wqkT[b][h*52+m][c] = SCALE * sum_d q_w[c][h*64+d] * k[b][h][m][d]  (bf16)
// ---------------------------------------------------------------------------
__global__ __launch_bounds__(256) void k_wqk(const float* __restrict__ kv,
                                             const float* __restrict__ q_w,
                                             uint16_t* __restrict__ wqkT) {
  int b = blockIdx.x, h = blockIdx.y;
  __shared__ float ksm[56 * 64];
  for (int idx = threadIdx.x; idx < 56 * 64; idx += 256) {
    int m = idx >> 6, d = idx & 63;
    ksm[idx] = (m < NK_) ? kv[((size_t)(b * NK_ + m)) * 1024 + h * HD_ + d] : 0.f;
  }
  __syncthreads();
#pragma unroll
  for (int cc = 0; cc < 2; ++cc) {
    int c = threadIdx.x + cc * 256;
    float qrow[64];
    const float* qp = q_w + (size_t)c * C_ + h * HD_;
#pragma unroll
    for (int d = 0; d < 64; ++d) qrow[d] = qp[d];
    for (int mc = 0; mc < NK_; mc += 8) {
      int cnt = min(8, NK_ - mc);
      float acc[8] = {0,0,0,0,0,0,0,0};
      for (int d = 0; d < 64; ++d) {
        float q = qrow[d];
#pragma unroll
        for (int i = 0; i < 8; ++i) acc[i] += q * ksm[(mc + i) * 64 + d];
      }
      for (int i = 0; i < cnt; ++i)
        wqkT[((size_t)(b * J_ + h * JP_ + mc + i)) * C_ + c] = f2bf(acc[i] * SCALE_);
    }
  }
  for (int idx = threadIdx.x; idx < 3 * C_; idx += 256) {
    int rr = idx / C_, c = idx % C_;
    wqkT[((size_t)(b * J_ + h * JP_ + 49 + rr)) * C_ + c] = 0;
  }
}

// ---------------------------------------------------------------------------
// 4) wvT[b][c'][h*52+m] = sum_d v[b][h][m][d] * proj_w[h*64+d][c']  (bf16)
// ---------------------------------------------------------------------------
__global__ __launch_bounds__(256) void k_wv(const float* __restrict__ kv,
                                            const float* __restrict__ proj_w,
                                            uint16_t* __restrict__ wvT) {
  int b = blockIdx.x, h = blockIdx.y;
  __shared__ float vsm[56 * 64];
  for (int idx = threadIdx.x; idx < 56 * 64; idx += 256) {
    int m = idx >> 6, d = idx & 63;
    vsm[idx] = (m < NK_) ? kv[((size_t)(b * NK_ + m)) * 1024 + 512 + h * HD_ + d] : 0.f;
  }
  __syncthreads();
#pragma unroll
  for (int cc = 0; cc < 2; ++cc) {
    int c = threadIdx.x + cc * 256;  // output column c'
    for (int mc = 0; mc < NK_; mc += 8) {
      int cnt = min(8, NK_ - mc);
      float acc[8] = {0,0,0,0,0,0,0,0};
      for (int d = 0; d < 64; ++d) {
        float w = proj_w[(size_t)(h * HD_ + d) * C_ + c];
#pragma unroll
        for (int i = 0; i < 8; ++i) acc[i] += vsm[(mc + i) * 64 + d] * w;
      }
      uint16_t* dst = wvT + ((size_t)(b * C_ + c)) * J_ + h * JP_ + mc;
      if (cnt == 8) {
        uint32_t pk[4];
#pragma unroll
        for (int i = 0; i < 4; ++i)
          pk[i] = (uint32_t)f2bf(acc[2*i]) | ((uint32_t)f2bf(acc[2*i+1]) << 16);
        *(uint2*)(dst)     = make_uint2(pk[0], pk[1]);
        *(uint2*)(dst + 4) = make_uint2(pk[2], pk[3]);
      } else {
        for (int i = 0; i < cnt; ++i) dst[i] = f2bf(acc[i]);
      }
    }
    uint16_t* pd = wvT + ((size_t)(b * C_ + c)) * J_ + h * JP_ + 49;
    pd[0] = 0; pd[1] = 0; pd[2] = 0;
  }
}

// ---------------------------------------------------------------------------
// 5) GEMM1 + softmax (MFMA bf16), attn written fp32 padded J
// ---------------------------------------------------------------------------
__global__ __launch_bounds__(256) void k_attn(const float* __restrict__ x,
                                              const uint16_t* __restrict__ wqkT,
                                              const float* __restrict__ rel_bias,
                                              float* __restrict__ attn) {
  const int mt = blockIdx.x, ct = blockIdx.y, b = blockIdx.z;
  const int n0 = mt * 64, j0 = ct * 208;
  const int tid = threadIdx.x, wvid = tid >> 6, lane = tid & 63;
  __shared__ __align__(16) char smem[64 * 212 * 4];   // 54272 B; staging aliased
  uint32_t* A32 = (uint32_t*)smem;          // [64][20] u32 (2 bf16 each)
  uint32_t* B32 = A32 + 64 * 20;            // [208][20]
  float* Ss = (float*)smem;                 // [64][212] epilogue (aliases staging)

  floatx4 acc[13];
#pragma unroll
  for (int t = 0; t < 13; ++t) acc[t] = (floatx4){0.f,0.f,0.f,0.f};

  const int an = tid & 63, acp = tid >> 6;
  for (int ks = 0; ks < 16; ++ks) {
    const int c0 = ks * 32;
    __syncthreads();
    {
      const float* xb = x + ((size_t)b * C_ + c0 + acp * 8) * N_ + n0 + an;
      uint32_t pk[4];
#pragma unroll
      for (int jj = 0; jj < 4; ++jj) {
        float f0 = xb[(size_t)(2*jj) * N_];
        float f1 = xb[(size_t)(2*jj+1) * N_];
        pk[jj] = (uint32_t)f2bf(f0) | ((uint32_t)f2bf(f1) << 16);
      }
      *(uint4*)&A32[an * 20 + acp * 4] = make_uint4(pk[0], pk[1], pk[2], pk[3]);
    }
    for (int idx = tid; idx < 832; idx += 256) {
      int jl = idx >> 2, q = idx & 3;
      uint4 v = *(const uint4*)(wqkT + ((size_t)b * J_ + j0 + jl) * C_ + c0 + q * 8);
      *(uint4*)&B32[jl * 20 + q * 4] = v;
    }
    __syncthreads();
    short8 af = *(const short8*)&A32[(wvid * 16 + (lane & 15)) * 20 + (lane >> 4) * 4];
#pragma unroll
    for (int t = 0; t < 13; ++t) {
      short8 bfb = *(const short8*)&B32[(16 * t + (lane & 15)) * 20 + (lane >> 4) * 4];
      acc[t] = __builtin_amdgcn_mfma_f32_16x16x32_bf16(af, bfb, acc[t], 0, 0, 0);
    }
  }
  __syncthreads();
  {
    const int rb = wvid * 16 + ((lane >> 4) << 2), cb = lane & 15;
#pragma unroll
    for (int t = 0; t < 13; ++t)
#pragma unroll
      for (int r2 = 0; r2 < 4; ++r2)
        Ss[(rb + r2) * 212 + t * 16 + cb] = acc[t][r2];
  }
  __syncthreads();
  {
    const int row = tid >> 2, hh = tid & 3;
    const int n = n0 + row;
    const float* bias = rel_bias + (size_t)n * NK_;
    float* srow = &Ss[row * 212 + hh * JP_];
    float mx = -1e30f;
    for (int m = 0; m < NK_; ++m) mx = fmaxf(mx, srow[m] + bias[m]);
    float sum = 0.f;
    for (int m = 0; m < NK_; ++m) { float e = __expf(srow[m] + bias[m] - mx); srow[m] = e; sum += e; }
    float inv = 1.f / sum;
    float* dst = attn + ((size_t)b * N_ + n) * J_ + j0 + hh * JP_;
    for (int m = 0; m < NK_; ++m) dst[m] = srow[m] * inv;
    dst[49] = 0.f; dst[50] = 0.f; dst[51] = 0.f;
  }
}

// ---------------------------------------------------------------------------
// 6) gn1 stats
// ---------------------------------------------------------------------------
__global__ __launch_bounds__(256) void k_gn1stats(const float* __restrict__ attn,
                                                  const float* __restrict__ ew,
                                                  float* __restrict__ gsums) {
  int nt = blockIdx.x, b = blockIdx.y;  // 49 x 16
  __shared__ float ews[HID_ * NH_];
  __shared__ float red[4][8];
  for (int i = threadIdx.x; i < HID_ * NH_; i += 256) ews[i] = ew[i];
  __syncthreads();
  float s[3] = {0,0,0}, q[3] = {0,0,0};
  for (int task = threadIdx.x; task < 64 * NK_; task += 256) {
    int r = task / NK_, m = task % NK_;
    const float* ap = attn + ((size_t)b * N_ + nt * 64 + r) * J_ + m;
    float a[8];
#pragma unroll
    for (int h = 0; h < 8; ++h) a[h] = ap[h * JP_];
#pragma unroll
    for (int o = 0; o < HID_; ++o) {
      float v = 0.f;
#pragma unroll
      for (int h = 0; h < 8; ++h) v += ews[o * 8 + h] * a[h];
      s[o >> 3] += v; q[o >> 3] += v * v;
    }
  }
  int lane = threadIdx.x & 63, wvid = threadIdx.x >> 6;
#pragma unroll
  for (int g = 0; g < 3; ++g) {
    float vs = s[g], vq = q[g];
#pragma unroll
    for (int off = 32; off; off >>= 1) { vs += __shfl_down(vs, off, 64); vq += __shfl_down(vq, off, 64); }
    if (lane == 0) { red[wvid][g*2] = vs; red[wvid][g*2+1] = vq; }
  }
  __syncthreads();
  if (threadIdx.x < 6) {
    float t = red[0][threadIdx.x] + red[1][threadIdx.x] + red[2][threadIdx.x] + red[3][threadIdx.x];
    atomicAdd(&gsums[b * 6 + threadIdx.x], t);
  }
}

// ---------------------------------------------------------------------------
// 7a) DLA pass 0: per (row-tile 16, b, group g of 8 ch):
//     h1(group) -> LDS [18][8][53] fp32 (zero-padded cols), dw 3x3 stencil,
//     accumulate gn2 sum/sumsq for group g.
// ---------------------------------------------------------------------------
__global__ __launch_bounds__(256) void k_dla0(const float* __restrict__ attn,
    const float* __restrict__ ew, const float* __restrict__ gn1_s,
    const float* __restrict__ gn1_b, const float* __restrict__ dww,
    const float* __restrict__ gn1sums, float* __restrict__ gn2sums) {
  const int nt = blockIdx.x, b = blockIdx.y, g = blockIdx.z;  // 196 x 16 x 3
  const int n0 = nt * 16;
  __shared__ float h1s[18 * 8 * 53];   // 30528 B
  __shared__ float red[4][2];
  // gn1 affine for this group's 8 channels (uniform -> scalar regs)
  float al[8], be[8];
  {
    float s = gn1sums[b*6 + g*2], qq = gn1sums[b*6 + g*2 + 1];
    float mean = s * (1.f / CNT_);
    float var = qq * (1.f / CNT_) - mean * mean;
    float inv = rsqrtf(var + EPS_);
#pragma unroll
    for (int o = 0; o < 8; ++o) {
      al[o] = inv * gn1_s[g*8 + o];
      be[o] = gn1_b[g*8 + o] - (s * (1.f / CNT_)) * al[o];
    }
  }
  // phase A: h1 rows n0-1..n0+16 -> LDS cols 1..49
  for (int task = threadIdx.x; task < 18 * NK_; task += 256) {
    int r = task / NK_, m = task % NK_;
    int n = n0 - 1 + r;
    if (n < 0 || n >= N_) {
#pragma unroll
      for (int o = 0; o < 8; ++o) h1s[(r*8+o)*53 + 1 + m] = 0.f;
    } else {
      const float* ap = attn + ((size_t)b * N_ + n) * J_ + m;
      float a[8];
#pragma unroll
      for (int h = 0; h < 8; ++h) a[h] = ap[h * JP_];
#pragma unroll
      for (int o = 0; o < 8; ++o) {
        float v = 0.f;
#pragma unroll
        for (int h = 0; h < 8; ++h) v += ew[(g*8+o)*8 + h] * a[h];
        float z = v * al[o] + be[o];
        h1s[(r*8+o)*53 + 1 + m] = z * sigm(z);
      }
    }
  }
  for (int idx = threadIdx.x; idx < 18 * 8 * 2; idx += 256)
    h1s[(idx >> 1) * 53 + (idx & 1) * 50] = 0.f;
  __syncthreads();
  // phase B: stencil + gn2 stats
  const int row = threadIdx.x >> 4, mg = threadIdx.x & 15;
  const int mstart = mg * 3, mcnt = (mg == 15) ? 4 : 3;
  float s0 = 0.f, q0 = 0.f;
#pragma unroll
  for (int mi = 0; mi < 4; ++mi) {
    if (mi >= mcnt) break;
    int m = mstart + mi;
#pragma unroll
    for (int o = 0; o < 8; ++o) {
      const float* wp = dww + (g*8+o)*9;
      float a2 = 0.f;
#pragma unroll
      for (int dr = 0; dr < 3; ++dr) {
        const float* hp = &h1s[((row+dr)*8+o)*53 + m];
        a2 += hp[0]*wp[dr*3+0] + hp[1]*wp[dr*3+1] + hp[2]*wp[dr*3+2];
      }
      s0 += a2; q0 += a2 * a2;
    }
  }
  int lane = threadIdx.x & 63, wvid = threadIdx.x >> 6;
#pragma unroll
  for (int off = 32; off; off >>= 1) { s0 += __shfl_down(s0, off, 64); q0 += __shfl_down(q0, off, 64); }
  if (lane == 0) { red[wvid][0] = s0; red[wvid][1] = q0; }
  __syncthreads();
  if (threadIdx.x < 2) {
    float t = red[0][threadIdx.x] + red[1][threadIdx.x] + red[2][threadIdx.x] + red[3][threadIdx.x];
    atomicAdd(&gn2sums[b*6 + g*2 + threadIdx.x], t);
  }
}

// ---------------------------------------------------------------------------
// 7b) DLA pass 1: per (row-tile 16, b): loop over 3 groups, recompute h1(g),
//     stencil -> gn2 affine -> swish -> accumulate reduce into racc[4][8]
//     registers; epilogue writes bf16 rbuf (padded J) + gn3 sums.
// ---------------------------------------------------------------------------
__global__ __launch_bounds__(256) void k_dla1(const float* __restrict__ attn,
    const float* __restrict__ ew, const float* __restrict__ gn1_s,
    const float* __restrict__ gn1_b, const float* __restrict__ dww,
    const float* __restrict__ gn1sums, const float* __restrict__ gn2_s,
    const float* __restrict__ gn2_b, const float* __restrict__ gn2sums,
    const float* __restrict__ rww, float* __restrict__ gn3sums,
    uint16_t* __restrict__ rbuf) {
  const int nt = blockIdx.x, b = blockIdx.y;  // 196 x 16
  const int n0 = nt * 16;
  __shared__ float h1s[18 * 8 * 53];
  __shared__ float red[4][2];
  const int row = threadIdx.x >> 4, mg = threadIdx.x & 15;
  const int mstart = mg * 3, mcnt = (mg == 15) ? 4 : 3;
  float racc[4][8];
#pragma unroll
  for (int mi = 0; mi < 4; ++mi)
#pragma unroll
    for (int p = 0; p < 8; ++p) racc[mi][p] = 0.f;

  for (int g = 0; g < 3; ++g) {
    float al[8], be[8], al2[8], be2[8];
    {
      float s = gn1sums[b*6 + g*2], qq = gn1sums[b*6 + g*2 + 1];
      float mean = s * (1.f / CNT_);
      float var = qq * (1.f / CNT_) - mean * mean;
      float inv = rsqrtf(var + EPS_);
#pragma unroll
      for (int o = 0; o < 8; ++o) {
        al[o] = inv * gn1_s[g*8 + o];
        be[o] = gn1_b[g*8 + o] - mean * al[o];
      }
      float s2 = gn2sums[b*6 + g*2], qq2 = gn2sums[b*6 + g*2 + 1];
      float mean2 = s2 * (1.f / CNT_);
      float var2 = qq2 * (1.f / CNT_) - mean2 * mean2;
      float inv2 = rsqrtf(var2 + EPS_);
#pragma unroll
      for (int o = 0; o < 8; ++o) {
        al2[o] = inv2 * gn2_s[g*8 + o];
        be2[o] = gn2_b[g*8 + o] - mean2 * al2[o];
      }
    }
    __syncthreads();  // protect LDS from previous g's readers
    for (int task = threadIdx.x; task < 18 * NK_; task += 256) {
      int r = task / NK_, m = task % NK_;
      int n = n0 - 1 + r;
      if (n < 0 || n >= N_) {
#pragma unroll
        for (int o = 0; o < 8; ++o) h1s[(r*8+o)*53 + 1 + m] = 0.f;
      } else {
        const float* ap = attn + ((size_t)b * N_ + n) * J_ + m;
        float a[8];
#pragma unroll
        for (int h = 0; h < 8; ++h) a[h] = ap[h * JP_];
#pragma unroll
        for (int o = 0; o < 8; ++o) {
          float v = 0.f;
#pragma unroll
          for (int h = 0; h < 8; ++h) v += ew[(g*8+o)*8 + h] * a[h];
          float z = v * al[o] + be[o];
          h1s[(r*8+o)*53 + 1 + m] = z * sigm(z);
        }
      }
    }
    for (int idx = threadIdx.x; idx < 18 * 8 * 2; idx += 256)
      h1s[(idx >> 1) * 53 + (idx & 1) * 50] = 0.f;
    __syncthreads();
#pragma unroll
    for (int mi = 0; mi < 4; ++mi) {
      if (mi >= mcnt) break;
      int m = mstart + mi;
#pragma unroll
      for (int o = 0; o < 8; ++o) {
        const float* wp = dww + (g*8+o)*9;
        float a2 = 0.f;
#pragma unroll
        for (int dr = 0; dr < 3; ++dr) {
          const float* hp = &h1s[((row+dr)*8+o)*53 + m];
          a2 += hp[0]*wp[dr*3+0] + hp[1]*wp[dr*3+1] + hp[2]*wp[dr*3+2];
        }
        float z = a2 * al2[o] + be2[o];
        float sw = z * sigm(z);
#pragma unroll
        for (int p = 0; p < 8; ++p) racc[mi][p] += rww[p*HID_ + g*8 + o] * sw;
      }
    }
  }
  // epilogue: write bf16 r (padded J layout) + gn3 sums
  float sr = 0.f, qr = 0.f;
  const int n = n0 + row;
  uint16_t* dstbase = rbuf + ((size_t)b * N_ + n) * J_;
#pragma unroll
  for (int mi = 0; mi < 4; ++mi) {
    if (mi >= mcnt) break;
    int m = mstart + mi;
#pragma unroll
    for (int p = 0; p < 8; ++p) {
      float v = racc[mi][p];
      dstbase[p * JP_ + m] = f2bf(v);
      sr += v; qr += v * v;
    }
  }
  if (mg == 15) {
#pragma unroll
    for (int p = 0; p < 8; ++p) {
      dstbase[p * JP_ + 49] = 0; dstbase[p * JP_ + 50] = 0; dstbase[p * JP_ + 51] = 0;
    }
  }
  int lane = threadIdx.x & 63, wvid = threadIdx.x >> 6;
#pragma unroll
  for (int off = 32; off; off >>= 1) { sr += __shfl_down(sr, off, 64); qr += __shfl_down(qr, off, 64); }
  if (lane == 0) { red[wvid][0] = sr; red[wvid][1] = qr; }
  __syncthreads();
  if (threadIdx.x < 2) {
    float t = red[0][threadIdx.x] + red[1][threadIdx.x] + red[2][threadIdx.x] + red[3][threadIdx.x];
    atomicAdd(&gn3sums[b*2 + threadIdx.x], t);
  }
}

// ---------------------------------------------------------------------------
// 8) GEMM2: out[b][n][c'] = sum_j gn3(r)[n][j] * wvT[b][c'][j] + proj_b[c']
// ---------------------------------------------------------------------------
__global__ __launch_bounds__(256) void k_out(const uint16_t* __restrict__ rr,
    const uint16_t* __restrict__ wvT, const float* __restrict__ gn3sums,
    const float* __restrict__ gn3_s, const float* __restrict__ gn3_b,
    const float* __restrict__ proj_b, float* __restrict__ outp) {
  const int mt = blockIdx.x, ct = blockIdx.y, b = blockIdx.z;
  const int n0 = mt * 64, c0 = ct * 128;
  const int tid = threadIdx.x, wvid = tid >> 6, lane = tid & 63;
  __shared__ __align__(16) uint32_t A32[64 * 20];
  __shared__ __align__(16) uint32_t B32[128 * 20];
  __shared__ float ab3[J_ * 2];
  {
    float ssum = gn3sums[b*2], sq = gn3sums[b*2+1];
    float mean = ssum * (1.f / CNT_);
    float var = sq * (1.f / CNT_) - mean * mean;
    float inv = rsqrtf(var + EPS_);
    for (int j = tid; j < J_; j += 256) {
      int h = j / JP_;
      float al = inv * gn3_s[h];
      ab3[j*2] = al; ab3[j*2+1] = gn3_b[h] - mean * al;
    }
  }
  floatx4 acc[8];
#pragma unroll
  for (int t = 0; t < 8; ++t) acc[t] = (floatx4){0.f,0.f,0.f,0.f};
  const int an = tid >> 2, acp = tid & 3;
  for (int ks = 0; ks < 13; ++ks) {
    const int k0 = ks * 32;
    __syncthreads();
    {
      const uint16_t* src = rr + ((size_t)b * N_ + n0 + an) * J_ + k0 + acp * 8;
      uint4 v = *(const uint4*)src;
      uint32_t raw[4] = {v.x, v.y, v.z, v.w};
      uint32_t pk[4];
#pragma unroll
      for (int jj = 0; jj < 4; ++jj) {
        int j = k0 + acp * 8 + jj * 2;
        float f0 = bf2f((uint16_t)(raw[jj] & 0xFFFFu)) * ab3[j*2]     + ab3[j*2+1];
        float f1 = bf2f((uint16_t)(raw[jj] >> 16))     * ab3[(j+1)*2] + ab3[(j+1)*2+1];
        pk[jj] = (uint32_t)f2bf(f0) | ((uint32_t)f2bf(f1) << 16);
      }
      *(uint4*)&A32[an * 20 + acp * 4] = make_uint4(pk[0], pk[1], pk[2], pk[3]);
    }
    for (int idx = tid; idx < 128 * 4; idx += 256) {
      int rw2 = idx >> 2, q = idx & 3;
      uint4 v = *(const uint4*)(wvT + ((size_t)b * C_ + c0 + rw2) * J_ + k0 + q * 8);
      *(uint4*)&B32[rw2 * 20 + q * 4] = v;
    }
    __syncthreads();
    short8 af = *(const short8*)&A32[(wvid * 16 + (lane & 15)) * 20 + (lane >> 4) * 4];
#pragma unroll
    for (int t = 0; t < 8; ++t) {
      short8 bfb = *(const short8*)&B32[(t * 16 + (lane & 15)) * 20 + (lane >> 4) * 4];
      acc[t] = __builtin_amdgcn_mfma_f32_16x16x32_bf16(af, bfb, acc[t], 0, 0, 0);
    }
  }
  const int rb = wvid * 16 + ((lane >> 4) << 2);
#pragma unroll
  for (int t = 0; t < 8; ++t) {
    int c = c0 + t * 16 + (lane & 15);
    float pb = proj_b[c];
#pragma unroll
    for (int r2 = 0; r2 < 4; ++r2)
      outp[((size_t)b * N_ + n0 + rb + r2) * C_ + c] = acc[t][r2] + pb;
  }
}

// ---------------------------------------------------------------------------
extern "C" void kernel_launch(void* const* d_in, const int* in_sizes, int n_in,
                              void* d_out, int out_size, void* d_ws, size_t ws_size,
                              hipStream_t stream) {
  (void)in_sizes; (void)n_in; (void)out_size;
  const float* x      = (const float*)d_in[0];
  const float* q_w    = (const float*)d_in[1];
  const float* down_w = (const float*)d_in[2];
  const float* kv_w   = (const float*)d_in[3];
  const float* proj_w = (const float*)d_in[4];
  const float* proj_b = (const float*)d_in[5];
  const float* rel_b  = (const float*)d_in[6];
  const float* ew     = (const float*)d_in[7];
  const float* gn1_s  = (const float*)d_in[8];
  const float* gn1_b  = (const float*)d_in[9];
  const float* dw_w   = (const float*)d_in[10];
  const float* gn2_s  = (const float*)d_in[11];
  const float* gn2_b  = (const float*)d_in[12];
  const float* red_w  = (const float*)d_in[13];
  const float* gn3_s  = (const float*)d_in[14];
  const float* gn3_b  = (const float*)d_in[15];
  float* outp = (float*)d_out;

  const size_t NEEDED = 143688704;  // ~137 MiB
  if (ws_size < NEEDED) return;

  char* ws = (char*)d_ws;
  float*    kvx   = (float*)(ws);                    //  1,605,632 B
  float*    kv    = (float*)(ws + 1605632);          //  3,211,264 B
  uint16_t* wqkT  = (uint16_t*)(ws + 4816896);       //  6,815,744 B
  uint16_t* wvT   = (uint16_t*)(ws + 11632640);      //  6,815,744 B
  float*    attn  = (float*)(ws + 18448384);         // 83,492,864 B
  uint16_t* rbuf  = (uint16_t*)(ws + 101941248);     // 41,746,432 B
  float*    stats = (float*)(ws + 143687680);        //      1,024 B
  float* gn1sums = stats;        // 16*6
  float* gn2sums = stats + 96;   // 16*6
  float* gn3sums = stats + 192;  // 16*2

  hipMemsetAsync(stats, 0, 1024, stream);
  k_kvx<<<1568, 256, 0, stream>>>(x, down_w, kvx);
  k_kv<<<dim3(16, 7), 256, 0, stream>>>(kvx, kv_w, kv);
  k_wqk<<<dim3(16, 8), 256, 0, stream>>>(kv, q_w, wqkT);
  k_wv<<<dim3(16, 8), 256, 0, stream>>>(kv, proj_w, wvT);
  k_attn<<<dim3(49, 2, 16), 256, 0, stream>>>(x, wqkT, rel_b, attn);
  k_gn1stats<<<dim3(49, 16), 256, 0, stream>>>(attn, ew, gn1sums);
  k_dla0<<<dim3(196, 16, 3), 256, 0, stream>>>(attn, ew, gn1_s, gn1_b, dw_w,
                                               gn1sums, gn2sums);
  k_dla1<<<dim3(196, 16), 256, 0, stream>>>(attn, ew, gn1_s, gn1_b, dw_w,
                                            gn1sums, gn2_s, gn2_b, gn2sums,
                                            red_w, gn3sums, rbuf);
  k_out<<<dim3(49, 4, 16), 256, 0, stream>>>(rbuf, wvT, gn3sums, gn3_s, gn3_b, proj_b, outp);
}

// Round 3
// 1163.499 us; speedup vs baseline: 1.7022x; 1.1536x over previous
//
#include <hip/hip_runtime.h>
#include <hip/hip_bf16.h>
#include <stdint.h>

// Problem constants
#define B_    16
#define C_    512
#define HIMG  56
#define N_    3136
#define NK_   49
#define NH_   8
#define HD_   64
#define JP_   52          // padded NK (49 -> 52) so 8*52 = 416 = 13*32
#define J_    416
#define HID_  24
#define MP_   50          // attn pixel-row stride (m-dim padded 49 -> 50)
#define CNT_  1229312.0f  // 8 * 3136 * 49 (elements per group-norm group)
#define EPS_  1e-5f
#define SCALE_ 0.125f     // HEAD_DIM^-0.5

typedef __attribute__((ext_vector_type(8))) short short8;
typedef __attribute__((ext_vector_type(4))) float floatx4;

static __device__ __forceinline__ uint16_t f2bf(float f) {
  uint32_t u = __builtin_bit_cast(uint32_t, f);
  u = (u + 0x7FFFu + ((u >> 16) & 1u)) >> 16;
  return (uint16_t)u;
}
static __device__ __forceinline__ float bf2f(uint16_t h) {
  uint32_t u = ((uint32_t)h) << 16;
  return __builtin_bit_cast(float, u);
}
static __device__ __forceinline__ float swishf(float z) {
  // z * sigmoid(z) with v_rcp_f32 (1-ulp) instead of IEEE divide
  return z * __builtin_amdgcn_rcpf(1.f + __expf(-z));
}

// gn1 affine (al,be) for group g's 8 channels from per-batch moments
// moms[b*44 + 0..7] = M1[h], moms[b*44 + 8..43] = upper-tri M2[h<=h2]
static __device__ __forceinline__ void gn1_affine(const float* __restrict__ moms,
    const float* __restrict__ ew, const float* __restrict__ gs,
    const float* __restrict__ gb, int b, int g, float* al, float* be) {
  float m1[8];
#pragma unroll
  for (int h = 0; h < 8; ++h) m1[h] = moms[b * 44 + h];
  float sum = 0.f, ssq = 0.f;
#pragma unroll
  for (int o2 = 0; o2 < 8; ++o2) {
    int o = g * 8 + o2;
    float e[8];
#pragma unroll
    for (int h = 0; h < 8; ++h) e[h] = ew[o * 8 + h];
    float so = 0.f;
#pragma unroll
    for (int h = 0; h < 8; ++h) so += e[h] * m1[h];
    sum += so;
    int idx = 8;
#pragma unroll
    for (int h = 0; h < 8; ++h)
#pragma unroll
      for (int h2 = h; h2 < 8; ++h2) {
        float cf = e[h] * e[h2] * ((h == h2) ? 1.f : 2.f);
        ssq += cf * moms[b * 44 + idx];
        ++idx;
      }
  }
  float mean = sum * (1.f / CNT_);
  float var = ssq * (1.f / CNT_) - mean * mean;
  float inv = rsqrtf(var + EPS_);
#pragma unroll
  for (int o2 = 0; o2 < 8; ++o2) {
    al[o2] = inv * gs[g * 8 + o2];
    be[o2] = gb[g * 8 + o2] - mean * al[o2];
  }
}

// ---------------------------------------------------------------------------
// 1) kvx[b][m][c] = depthwise 8x8/stride-8 downsample
// ---------------------------------------------------------------------------
__global__ __launch_bounds__(256) void k_kvx(const float* __restrict__ x,
                                             const float* __restrict__ dw,
                                             float* __restrict__ kvx) {
  int g = blockIdx.x * 256 + threadIdx.x;           // B*C*NK = 401408 exact
  int b = g / (C_ * NK_);
  int rem = g % (C_ * NK_);
  int c = rem / NK_;
  int m = rem % NK_;
  int ph = m / 7, pw = m % 7;
  const float* xp = x + ((size_t)(b * C_ + c)) * N_ + (ph * 8) * HIMG + pw * 8;
  const float* wp = dw + c * 64;
  float acc = 0.f;
#pragma unroll
  for (int i = 0; i < 8; ++i) {
    float4 a  = *(const float4*)(xp + i * HIMG);
    float4 bq = *(const float4*)(xp + i * HIMG + 4);
    acc += a.x*wp[i*8+0] + a.y*wp[i*8+1] + a.z*wp[i*8+2] + a.w*wp[i*8+3]
         + bq.x*wp[i*8+4] + bq.y*wp[i*8+5] + bq.z*wp[i*8+6] + bq.w*wp[i*8+7];
  }
  kvx[((size_t)(b * NK_ + m)) * C_ + c] = acc;
}

// ---------------------------------------------------------------------------
// 2) kv[b][m][col] = sum_c kvx[b][m][c] * kv_w[c][col]   (col 0..1023)
// ---------------------------------------------------------------------------
__global__ __launch_bounds__(256) void k_kv(const float* __restrict__ kvx,
                                            const float* __restrict__ kv_w,
                                            float* __restrict__ kv) {
  int b = blockIdx.x;   // 16
  int rg = blockIdx.y;  // 7 row groups of 8 (last has 1)
  int m0 = rg * 8;
  int nr = min(8, NK_ - m0);
  __shared__ float ks[8 * C_];
  for (int idx = threadIdx.x; idx < 8 * C_; idx += 256)
    ks[idx] = (idx < nr * C_) ? kvx[((size_t)(b * NK_ + m0)) * C_ + idx] : 0.f;
  __syncthreads();
  int j4 = threadIdx.x * 4;
  float4 acc[8];
#pragma unroll
  for (int i = 0; i < 8; ++i) acc[i] = make_float4(0,0,0,0);
  for (int c = 0; c < C_; ++c) {
    float4 w = *(const float4*)(kv_w + (size_t)c * 1024 + j4);
#pragma unroll
    for (int i = 0; i < 8; ++i) {
      float a = ks[i * C_ + c];
      acc[i].x += a*w.x; acc[i].y += a*w.y; acc[i].z += a*w.z; acc[i].w += a*w.w;
    }
  }
  for (int i = 0; i < nr; ++i)
    *(float4*)(kv + ((size_t)(b * NK_ + m0 + i)) * 1024 + j4) = acc[i];
}

// ---------------------------------------------------------------------------
// 3) wqkT[b][h*52+m][c] = SCALE * sum_d q_w[c][h*64+d] * k[b][h][m][d]  (bf16)
// ---------------------------------------------------------------------------
__global__ __launch_bounds__(256) void k_wqk(const float* __restrict__ kv,
                                             const float* __restrict__ q_w,
                                             uint16_t* __restrict__ wqkT) {
  int b = blockIdx.x, h = blockIdx.y;
  __shared__ float ksm[56 * 64];
  for (int idx = threadIdx.x; idx < 56 * 64; idx += 256) {
    int m = idx >> 6, d = idx & 63;
    ksm[idx] = (m < NK_) ? kv[((size_t)(b * NK_ + m)) * 1024 + h * HD_ + d] : 0.f;
  }
  __syncthreads();
#pragma unroll
  for (int cc = 0; cc < 2; ++cc) {
    int c = threadIdx.x + cc * 256;
    float qrow[64];
    const float* qp = q_w + (size_t)c * C_ + h * HD_;
#pragma unroll
    for (int d = 0; d < 64; ++d) qrow[d] = qp[d];
    for (int mc = 0; mc < NK_; mc += 8) {
      int cnt = min(8, NK_ - mc);
      float acc[8] = {0,0,0,0,0,0,0,0};
      for (int d = 0; d < 64; ++d) {
        float q = qrow[d];
#pragma unroll
        for (int i = 0; i < 8; ++i) acc[i] += q * ksm[(mc + i) * 64 + d];
      }
      for (int i = 0; i < cnt; ++i)
        wqkT[((size_t)(b * J_ + h * JP_ + mc + i)) * C_ + c] = f2bf(acc[i] * SCALE_);
    }
  }
  for (int idx = threadIdx.x; idx < 3 * C_; idx += 256) {
    int rr = idx / C_, c = idx % C_;
    wqkT[((size_t)(b * J_ + h * JP_ + 49 + rr)) * C_ + c] = 0;
  }
}

// ---------------------------------------------------------------------------
// 4) wvT[b][c'][h*52+m] = sum_d v[b][h][m][d] * proj_w[h*64+d][c']  (bf16)
// ---------------------------------------------------------------------------
__global__ __launch_bounds__(256) void k_wv(const float* __restrict__ kv,
                                            const float* __restrict__ proj_w,
                                            uint16_t* __restrict__ wvT) {
  int b = blockIdx.x, h = blockIdx.y;
  __shared__ float vsm[56 * 64];
  for (int idx = threadIdx.x; idx < 56 * 64; idx += 256) {
    int m = idx >> 6, d = idx & 63;
    vsm[idx] = (m < NK_) ? kv[((size_t)(b * NK_ + m)) * 1024 + 512 + h * HD_ + d] : 0.f;
  }
  __syncthreads();
#pragma unroll
  for (int cc = 0; cc < 2; ++cc) {
    int c = threadIdx.x + cc * 256;  // output column c'
    for (int mc = 0; mc < NK_; mc += 8) {
      int cnt = min(8, NK_ - mc);
      float acc[8] = {0,0,0,0,0,0,0,0};
      for (int d = 0; d < 64; ++d) {
        float w = proj_w[(size_t)(h * HD_ + d) * C_ + c];
#pragma unroll
        for (int i = 0; i < 8; ++i) acc[i] += vsm[(mc + i) * 64 + d] * w;
      }
      uint16_t* dst = wvT + ((size_t)(b * C_ + c)) * J_ + h * JP_ + mc;
      if (cnt == 8) {
        uint32_t pk[4];
#pragma unroll
        for (int i = 0; i < 4; ++i)
          pk[i] = (uint32_t)f2bf(acc[2*i]) | ((uint32_t)f2bf(acc[2*i+1]) << 16);
        *(uint2*)(dst)     = make_uint2(pk[0], pk[1]);
        *(uint2*)(dst + 4) = make_uint2(pk[2], pk[3]);
      } else {
        for (int i = 0; i < cnt; ++i) dst[i] = f2bf(acc[i]);
      }
    }
    uint16_t* pd = wvT + ((size_t)(b * C_ + c)) * J_ + h * JP_ + 49;
    pd[0] = 0; pd[1] = 0; pd[2] = 0;
  }
}

// ---------------------------------------------------------------------------
// 5) GEMM1 + softmax (MFMA bf16); attn written fp32 as [b][n][50][8h]
// ---------------------------------------------------------------------------
__global__ __launch_bounds__(256) void k_attn(const float* __restrict__ x,
                                              const uint16_t* __restrict__ wqkT,
                                              const float* __restrict__ rel_bias,
                                              float* __restrict__ attn) {
  const int mt = blockIdx.x, ct = blockIdx.y, b = blockIdx.z;
  const int n0 = mt * 64, j0 = ct * 208;
  const int tid = threadIdx.x, wvid = tid >> 6, lane = tid & 63;
  __shared__ __align__(16) char smem[64 * 212 * 4];   // 54272 B; staging aliased
  uint32_t* A32 = (uint32_t*)smem;          // [64][20] u32 (2 bf16 each)
  uint32_t* B32 = A32 + 64 * 20;            // [208][20]
  float* Ss = (float*)smem;                 // [64][212] epilogue (aliases staging)

  floatx4 acc[13];
#pragma unroll
  for (int t = 0; t < 13; ++t) acc[t] = (floatx4){0.f,0.f,0.f,0.f};

  const int an = tid & 63, acp = tid >> 6;
  for (int ks = 0; ks < 16; ++ks) {
    const int c0 = ks * 32;
    __syncthreads();
    {
      const float* xb = x + ((size_t)b * C_ + c0 + acp * 8) * N_ + n0 + an;
      uint32_t pk[4];
#pragma unroll
      for (int jj = 0; jj < 4; ++jj) {
        float f0 = xb[(size_t)(2*jj) * N_];
        float f1 = xb[(size_t)(2*jj+1) * N_];
        pk[jj] = (uint32_t)f2bf(f0) | ((uint32_t)f2bf(f1) << 16);
      }
      *(uint4*)&A32[an * 20 + acp * 4] = make_uint4(pk[0], pk[1], pk[2], pk[3]);
    }
    for (int idx = tid; idx < 832; idx += 256) {
      int jl = idx >> 2, q = idx & 3;
      uint4 v = *(const uint4*)(wqkT + ((size_t)b * J_ + j0 + jl) * C_ + c0 + q * 8);
      *(uint4*)&B32[jl * 20 + q * 4] = v;
    }
    __syncthreads();
    short8 af = *(const short8*)&A32[(wvid * 16 + (lane & 15)) * 20 + (lane >> 4) * 4];
#pragma unroll
    for (int t = 0; t < 13; ++t) {
      short8 bfb = *(const short8*)&B32[(16 * t + (lane & 15)) * 20 + (lane >> 4) * 4];
      acc[t] = __builtin_amdgcn_mfma_f32_16x16x32_bf16(af, bfb, acc[t], 0, 0, 0);
    }
  }
  __syncthreads();
  {
    const int rb = wvid * 16 + ((lane >> 4) << 2), cb = lane & 15;
#pragma unroll
    for (int t = 0; t < 13; ++t)
#pragma unroll
      for (int r2 = 0; r2 < 4; ++r2)
        Ss[(rb + r2) * 212 + t * 16 + cb] = acc[t][r2];
  }
  __syncthreads();
  {
    const int row = tid >> 2, hh = tid & 3;
    const int n = n0 + row;
    const float* bias = rel_bias + (size_t)n * NK_;
    float* srow = &Ss[row * 212 + hh * JP_];
    float mx = -1e30f;
    for (int m = 0; m < NK_; ++m) mx = fmaxf(mx, srow[m] + bias[m]);
    float sum = 0.f;
    for (int m = 0; m < NK_; ++m) { float e = __expf(srow[m] + bias[m] - mx); srow[m] = e; sum += e; }
    float inv = 1.f / sum;
    for (int m = 0; m < NK_; ++m) srow[m] *= inv;
  }
  __syncthreads();
  // cooperative vectorized write: pixel layout [n][m][8h], this tile owns 4 heads
  for (int task = tid; task < 64 * NK_; task += 256) {
    int row = task / NK_, m = task % NK_;
    const float* sr = &Ss[row * 212];
    float4 v = make_float4(sr[m], sr[JP_ + m], sr[2 * JP_ + m], sr[3 * JP_ + m]);
    *(float4*)(attn + (((size_t)b * N_ + n0 + row) * MP_ + m) * 8 + ct * 4) = v;
  }
}

// ---------------------------------------------------------------------------
// 6) attn moments per batch: M1[h] = sum a[h]; M2 upper-tri = sum a[h]*a[h2]
// ---------------------------------------------------------------------------
__global__ __launch_bounds__(256) void k_moms(const float* __restrict__ attn,
                                              float* __restrict__ moms) {
  int nt = blockIdx.x, b = blockIdx.y;  // 49 x 16
  float vals[44];
#pragma unroll
  for (int k = 0; k < 44; ++k) vals[k] = 0.f;
  for (int task = threadIdx.x; task < 64 * NK_; task += 256) {
    int r = task / NK_, m = task % NK_;
    const float* ap = attn + (((size_t)b * N_ + nt * 64 + r) * MP_ + m) * 8;
    float4 a0 = *(const float4*)ap;
    float4 a1 = *(const float4*)(ap + 4);
    float a[8] = {a0.x, a0.y, a0.z, a0.w, a1.x, a1.y, a1.z, a1.w};
#pragma unroll
    for (int h = 0; h < 8; ++h) vals[h] += a[h];
    int idx = 8;
#pragma unroll
    for (int h = 0; h < 8; ++h)
#pragma unroll
      for (int h2 = h; h2 < 8; ++h2) { vals[idx] += a[h] * a[h2]; ++idx; }
  }
  __shared__ float red[4][44];
  int lane = threadIdx.x & 63, wvid = threadIdx.x >> 6;
#pragma unroll
  for (int k = 0; k < 44; ++k) {
#pragma unroll
    for (int off = 32; off; off >>= 1) vals[k] += __shfl_down(vals[k], off, 64);
  }
  if (lane == 0) {
#pragma unroll
    for (int k = 0; k < 44; ++k) red[wvid][k] = vals[k];
  }
  __syncthreads();
  if (threadIdx.x < 44) {
    float t = red[0][threadIdx.x] + red[1][threadIdx.x] + red[2][threadIdx.x] + red[3][threadIdx.x];
    atomicAdd(&moms[b * 44 + threadIdx.x], t);
  }
}

// ---------------------------------------------------------------------------
// 7a) DLA pass 0 per (16-row tile, b, group g): h1 -> LDS [18][51][8ch]
//     (zero-padded halo cols), dw 3x3 via vector LDS, gn2 sum/sumsq.
// ---------------------------------------------------------------------------
__global__ __launch_bounds__(256) void k_dla0(const float* __restrict__ attn,
    const float* __restrict__ ew, const float* __restrict__ gn1_s,
    const float* __restrict__ gn1_b, const float* __restrict__ dww,
    const float* __restrict__ moms, float* __restrict__ gn2sums) {
  const int nt = blockIdx.x, b = blockIdx.y, g = blockIdx.z;  // 196 x 16 x 3
  const int n0 = nt * 16;
  __shared__ __align__(16) float h1s[18 * 51 * 8];   // 29376 B
  __shared__ float red[4][2];
  float al[8], be[8];
  gn1_affine(moms, ew, gn1_s, gn1_b, b, g, al, be);
  // phase A: h1 rows n0-1..n0+16 -> cols 1..49, layout [r][col][8ch]
  for (int task = threadIdx.x; task < 18 * NK_; task += 256) {
    int r = task / NK_, m = task % NK_;
    int n = n0 - 1 + r;
    float h1v[8];
    if (n < 0 || n >= N_) {
#pragma unroll
      for (int o = 0; o < 8; ++o) h1v[o] = 0.f;
    } else {
      const float* ap = attn + (((size_t)b * N_ + n) * MP_ + m) * 8;
      float4 a0 = *(const float4*)ap;
      float4 a1 = *(const float4*)(ap + 4);
      float a[8] = {a0.x, a0.y, a0.z, a0.w, a1.x, a1.y, a1.z, a1.w};
#pragma unroll
      for (int o = 0; o < 8; ++o) {
        float v = 0.f;
#pragma unroll
        for (int h = 0; h < 8; ++h) v += ew[(g * 8 + o) * 8 + h] * a[h];
        h1v[o] = swishf(v * al[o] + be[o]);
      }
    }
    float* dst = &h1s[(r * 51 + m + 1) * 8];
    *(float4*)dst = make_float4(h1v[0], h1v[1], h1v[2], h1v[3]);
    *(float4*)(dst + 4) = make_float4(h1v[4], h1v[5], h1v[6], h1v[7]);
  }
  for (int idx = threadIdx.x; idx < 18 * 16; idx += 256) {
    int r = idx >> 4, c = idx & 15;
    h1s[(r * 51 + (c >> 3) * 50) * 8 + (c & 7)] = 0.f;
  }
  __syncthreads();
  // phase B: vectorized stencil
  const int row = threadIdx.x >> 4, mg = threadIdx.x & 15;
  const int m0 = mg * 3;
  const int mlim = (mg == 15) ? 4 : 3;
  float a2[4][8];
#pragma unroll
  for (int mi = 0; mi < 4; ++mi)
#pragma unroll
    for (int o = 0; o < 8; ++o) a2[mi][o] = 0.f;
#pragma unroll
  for (int dr = 0; dr < 3; ++dr) {
    float win[48];
    const float* src = &h1s[((row + dr) * 51 + m0) * 8];
#pragma unroll
    for (int k = 0; k < 12; ++k)
      *(float4*)&win[k * 4] = *(const float4*)(src + k * 4);
#pragma unroll
    for (int o = 0; o < 8; ++o) {
      float wa = dww[(g * 8 + o) * 9 + dr * 3 + 0];
      float wb = dww[(g * 8 + o) * 9 + dr * 3 + 1];
      float wc = dww[(g * 8 + o) * 9 + dr * 3 + 2];
#pragma unroll
      for (int mi = 0; mi < 4; ++mi)
        a2[mi][o] += win[mi * 8 + o] * wa + win[(mi + 1) * 8 + o] * wb + win[(mi + 2) * 8 + o] * wc;
    }
  }
  float s0 = 0.f, q0 = 0.f;
#pragma unroll
  for (int mi = 0; mi < 4; ++mi) {
    if (mi < mlim) {
#pragma unroll
      for (int o = 0; o < 8; ++o) { s0 += a2[mi][o]; q0 += a2[mi][o] * a2[mi][o]; }
    }
  }
  int lane = threadIdx.x & 63, wvid = threadIdx.x >> 6;
#pragma unroll
  for (int off = 32; off; off >>= 1) { s0 += __shfl_down(s0, off, 64); q0 += __shfl_down(q0, off, 64); }
  if (lane == 0) { red[wvid][0] = s0; red[wvid][1] = q0; }
  __syncthreads();
  if (threadIdx.x < 2) {
    float t = red[0][threadIdx.x] + red[1][threadIdx.x] + red[2][threadIdx.x] + red[3][threadIdx.x];
    atomicAdd(&gn2sums[b * 6 + g * 2 + threadIdx.x], t);
  }
}

// ---------------------------------------------------------------------------
// 7b) DLA pass 1 per (16-row tile, b): loop groups, stencil -> gn2 affine ->
//     swish -> reduce into racc; epilogue writes bf16 rbuf + gn3 sums.
// ---------------------------------------------------------------------------
__global__ __launch_bounds__(256) void k_dla1(const float* __restrict__ attn,
    const float* __restrict__ ew, const float* __restrict__ gn1_s,
    const float* __restrict__ gn1_b, const float* __restrict__ dww,
    const float* __restrict__ moms, const float* __restrict__ gn2_s,
    const float* __restrict__ gn2_b, const float* __restrict__ gn2sums,
    const float* __restrict__ rww, float* __restrict__ gn3sums,
    uint16_t* __restrict__ rbuf) {
  const int nt = blockIdx.x, b = blockIdx.y;  // 196 x 16
  const int n0 = nt * 16;
  __shared__ __align__(16) float h1s[18 * 51 * 8];
  __shared__ float red[4][2];
  const int row = threadIdx.x >> 4, mg = threadIdx.x & 15;
  const int m0 = mg * 3;
  const int mlim = (mg == 15) ? 4 : 3;
  float racc[4][8];
#pragma unroll
  for (int mi = 0; mi < 4; ++mi)
#pragma unroll
    for (int p = 0; p < 8; ++p) racc[mi][p] = 0.f;

  for (int g = 0; g < 3; ++g) {
    float al[8], be[8], al2[8], be2[8];
    gn1_affine(moms, ew, gn1_s, gn1_b, b, g, al, be);
    {
      float s2 = gn2sums[b * 6 + g * 2], qq2 = gn2sums[b * 6 + g * 2 + 1];
      float mean2 = s2 * (1.f / CNT_);
      float var2 = qq2 * (1.f / CNT_) - mean2 * mean2;
      float inv2 = rsqrtf(var2 + EPS_);
#pragma unroll
      for (int o = 0; o < 8; ++o) {
        al2[o] = inv2 * gn2_s[g * 8 + o];
        be2[o] = gn2_b[g * 8 + o] - mean2 * al2[o];
      }
    }
    __syncthreads();  // protect LDS from previous g's readers
    for (int task = threadIdx.x; task < 18 * NK_; task += 256) {
      int r = task / NK_, m = task % NK_;
      int n = n0 - 1 + r;
      float h1v[8];
      if (n < 0 || n >= N_) {
#pragma unroll
        for (int o = 0; o < 8; ++o) h1v[o] = 0.f;
      } else {
        const float* ap = attn + (((size_t)b * N_ + n) * MP_ + m) * 8;
        float4 a0 = *(const float4*)ap;
        float4 a1 = *(const float4*)(ap + 4);
        float a[8] = {a0.x, a0.y, a0.z, a0.w, a1.x, a1.y, a1.z, a1.w};
#pragma unroll
        for (int o = 0; o < 8; ++o) {
          float v = 0.f;
#pragma unroll
          for (int h = 0; h < 8; ++h) v += ew[(g * 8 + o) * 8 + h] * a[h];
          h1v[o] = swishf(v * al[o] + be[o]);
        }
      }
      float* dst = &h1s[(r * 51 + m + 1) * 8];
      *(float4*)dst = make_float4(h1v[0], h1v[1], h1v[2], h1v[3]);
      *(float4*)(dst + 4) = make_float4(h1v[4], h1v[5], h1v[6], h1v[7]);
    }
    for (int idx = threadIdx.x; idx < 18 * 16; idx += 256) {
      int r = idx >> 4, c = idx & 15;
      h1s[(r * 51 + (c >> 3) * 50) * 8 + (c & 7)] = 0.f;
    }
    __syncthreads();
    float a2[4][8];
#pragma unroll
    for (int mi = 0; mi < 4; ++mi)
#pragma unroll
      for (int o = 0; o < 8; ++o) a2[mi][o] = 0.f;
#pragma unroll
    for (int dr = 0; dr < 3; ++dr) {
      float win[48];
      const float* src = &h1s[((row + dr) * 51 + m0) * 8];
#pragma unroll
      for (int k = 0; k < 12; ++k)
        *(float4*)&win[k * 4] = *(const float4*)(src + k * 4);
#pragma unroll
      for (int o = 0; o < 8; ++o) {
        float wa = dww[(g * 8 + o) * 9 + dr * 3 + 0];
        float wb = dww[(g * 8 + o) * 9 + dr * 3 + 1];
        float wc = dww[(g * 8 + o) * 9 + dr * 3 + 2];
#pragma unroll
        for (int mi = 0; mi < 4; ++mi)
          a2[mi][o] += win[mi * 8 + o] * wa + win[(mi + 1) * 8 + o] * wb + win[(mi + 2) * 8 + o] * wc;
      }
    }
#pragma unroll
    for (int mi = 0; mi < 4; ++mi) {
      if (mi < mlim) {
#pragma unroll
        for (int o = 0; o < 8; ++o) {
          float sw = swishf(a2[mi][o] * al2[o] + be2[o]);
#pragma unroll
          for (int p = 0; p < 8; ++p) racc[mi][p] += rww[p * HID_ + g * 8 + o] * sw;
        }
      }
    }
  }
  // epilogue: write bf16 r (padded J layout) + gn3 sums
  float sr = 0.f, qr = 0.f;
  const int n = n0 + row;
  uint16_t* dstbase = rbuf + ((size_t)b * N_ + n) * J_;
#pragma unroll
  for (int mi = 0; mi < 4; ++mi) {
    if (mi < mlim) {
      int m = m0 + mi;
#pragma unroll
      for (int p = 0; p < 8; ++p) {
        float v = racc[mi][p];
        dstbase[p * JP_ + m] = f2bf(v);
        sr += v; qr += v * v;
      }
    }
  }
  if (mg == 15) {
#pragma unroll
    for (int p = 0; p < 8; ++p) {
      dstbase[p * JP_ + 49] = 0; dstbase[p * JP_ + 50] = 0; dstbase[p * JP_ + 51] = 0;
    }
  }
  int lane = threadIdx.x & 63, wvid = threadIdx.x >> 6;
#pragma unroll
  for (int off = 32; off; off >>= 1) { sr += __shfl_down(sr, off, 64); qr += __shfl_down(qr, off, 64); }
  if (lane == 0) { red[wvid][0] = sr; red[wvid][1] = qr; }
  __syncthreads();
  if (threadIdx.x < 2) {
    float t = red[0][threadIdx.x] + red[1][threadIdx.x] + red[2][threadIdx.x] + red[3][threadIdx.x];
    atomicAdd(&gn3sums[b * 2 + threadIdx.x], t);
  }
}

// ---------------------------------------------------------------------------
// 8) GEMM2: out[b][n][c'] = sum_j gn3(r)[n][j] * wvT[b][c'][j] + proj_b[c']
// ---------------------------------------------------------------------------
__global__ __launch_bounds__(256) void k_out(const uint16_t* __restrict__ rr,
    const uint16_t* __restrict__ wvT, const float* __restrict__ gn3sums,
    const float* __restrict__ gn3_s, const float* __restrict__ gn3_b,
    const float* __restrict__ proj_b, float* __restrict__ outp) {
  const int mt = blockIdx.x, ct = blockIdx.y, b = blockIdx.z;
  const int n0 = mt * 64, c0 = ct * 128;
  const int tid = threadIdx.x, wvid = tid >> 6, lane = tid & 63;
  __shared__ __align__(16) uint32_t A32[64 * 20];
  __shared__ __align__(16) uint32_t B32[128 * 20];
  __shared__ float ab3[J_ * 2];
  {
    float ssum = gn3sums[b*2], sq = gn3sums[b*2+1];
    float mean = ssum * (1.f / CNT_);
    float var = sq * (1.f / CNT_) - mean * mean;
    float inv = rsqrtf(var + EPS_);
    for (int j = tid; j < J_; j += 256) {
      int h = j / JP_;
      float al = inv * gn3_s[h];
      ab3[j*2] = al; ab3[j*2+1] = gn3_b[h] - mean * al;
    }
  }
  floatx4 acc[8];
#pragma unroll
  for (int t = 0; t < 8; ++t) acc[t] = (floatx4){0.f,0.f,0.f,0.f};
  const int an = tid >> 2, acp = tid & 3;
  for (int ks = 0; ks < 13; ++ks) {
    const int k0 = ks * 32;
    __syncthreads();
    {
      const uint16_t* src = rr + ((size_t)b * N_ + n0 + an) * J_ + k0 + acp * 8;
      uint4 v = *(const uint4*)src;
      uint32_t raw[4] = {v.x, v.y, v.z, v.w};
      uint32_t pk[4];
#pragma unroll
      for (int jj = 0; jj < 4; ++jj) {
        int j = k0 + acp * 8 + jj * 2;
        float f0 = bf2f((uint16_t)(raw[jj] & 0xFFFFu)) * ab3[j*2]     + ab3[j*2+1];
        float f1 = bf2f((uint16_t)(raw[jj] >> 16))     * ab3[(j+1)*2] + ab3[(j+1)*2+1];
        pk[jj] = (uint32_t)f2bf(f0) | ((uint32_t)f2bf(f1) << 16);
      }
      *(uint4*)&A32[an * 20 + acp * 4] = make_uint4(pk[0], pk[1], pk[2], pk[3]);
    }
    for (int idx = tid; idx < 128 * 4; idx += 256) {
      int rw2 = idx >> 2, q = idx & 3;
      uint4 v = *(const uint4*)(wvT + ((size_t)b * C_ + c0 + rw2) * J_ + k0 + q * 8);
      *(uint4*)&B32[rw2 * 20 + q * 4] = v;
    }
    __syncthreads();
    short8 af = *(const short8*)&A32[(wvid * 16 + (lane & 15)) * 20 + (lane >> 4) * 4];
#pragma unroll
    for (int t = 0; t < 8; ++t) {
      short8 bfb = *(const short8*)&B32[(t * 16 + (lane & 15)) * 20 + (lane >> 4) * 4];
      acc[t] = __builtin_amdgcn_mfma_f32_16x16x32_bf16(af, bfb, acc[t], 0, 0, 0);
    }
  }
  const int rb = wvid * 16 + ((lane >> 4) << 2);
#pragma unroll
  for (int t = 0; t < 8; ++t) {
    int c = c0 + t * 16 + (lane & 15);
    float pb = proj_b[c];
#pragma unroll
    for (int r2 = 0; r2 < 4; ++r2)
      outp[((size_t)b * N_ + n0 + rb + r2) * C_ + c] = acc[t][r2] + pb;
  }
}

// ---------------------------------------------------------------------------
extern "C" void kernel_launch(void* const* d_in, const int* in_sizes, int n_in,
                              void* d_out, int out_size, void* d_ws, size_t ws_size,
                              hipStream_t stream) {
  (void)in_sizes; (void)n_in; (void)out_size;
  const float* x      = (const float*)d_in[0];
  const float* q_w    = (const float*)d_in[1];
  const float* down_w = (const float*)d_in[2];
  const float* kv_w   = (const float*)d_in[3];
  const float* proj_w = (const float*)d_in[4];
  const float* proj_b = (const float*)d_in[5];
  const float* rel_b  = (const float*)d_in[6];
  const float* ew     = (const float*)d_in[7];
  const float* gn1_s  = (const float*)d_in[8];
  const float* gn1_b  = (const float*)d_in[9];
  const float* dw_w   = (const float*)d_in[10];
  const float* gn2_s  = (const float*)d_in[11];
  const float* gn2_b  = (const float*)d_in[12];
  const float* red_w  = (const float*)d_in[13];
  const float* gn3_s  = (const float*)d_in[14];
  const float* gn3_b  = (const float*)d_in[15];
  float* outp = (float*)d_out;

  const size_t NEEDED = 143688704;  // ~137 MiB (unchanged from R1)
  if (ws_size < NEEDED) return;

  char* ws = (char*)d_ws;
  float*    kvx   = (float*)(ws);                    //  1,605,632 B
  float*    kv    = (float*)(ws + 1605632);          //  3,211,264 B
  uint16_t* wqkT  = (uint16_t*)(ws + 4816896);       //  6,815,744 B
  uint16_t* wvT   = (uint16_t*)(ws + 11632640);      //  6,815,744 B
  float*    attn  = (float*)(ws + 18448384);         // 80,281,600 B ([b][n][50][8])
  float*    stats = (float*)(ws + 98729984);         //      4,096 B (in attn slot tail)
  uint16_t* rbuf  = (uint16_t*)(ws + 101941248);     // 41,746,432 B
  float* moms    = stats;         // 16*44
  float* gn2sums = stats + 704;   // 16*6
  float* gn3sums = stats + 800;   // 16*2

  hipMemsetAsync(stats, 0, 4096, stream);
  k_kvx<<<1568, 256, 0, stream>>>(x, down_w, kvx);
  k_kv<<<dim3(16, 7), 256, 0, stream>>>(kvx, kv_w, kv);
  k_wqk<<<dim3(16, 8), 256, 0, stream>>>(kv, q_w, wqkT);
  k_wv<<<dim3(16, 8), 256, 0, stream>>>(kv, proj_w, wvT);
  k_attn<<<dim3(49, 2, 16), 256, 0, stream>>>(x, wqkT, rel_b, attn);
  k_moms<<<dim3(49, 16), 256, 0, stream>>>(attn, moms);
  k_dla0<<<dim3(196, 16, 3), 256, 0, stream>>>(attn, ew, gn1_s, gn1_b, dw_w,
                                               moms, gn2sums);
  k_dla1<<<dim3(196, 16), 256, 0, stream>>>(attn, ew, gn1_s, gn1_b, dw_w,
                                            moms, gn2_s, gn2_b, gn2sums,
                                            red_w, gn3sums, rbuf);
  k_out<<<dim3(49, 4, 16), 256, 0, stream>>>(rbuf, wvT, gn3sums, gn3_s, gn3_b, proj_b, outp);
}